// Round 6
// baseline (699.419 us; speedup 1.0000x reference)
//
#include <hip/hip_runtime.h>
#include <hip/hip_bf16.h>

// GCN forward, CSR gather + MFMA GEMMs (bf16 hi/lo split for f32 accuracy):
//   hs = (X@W) * dnorm[v]
//   h_out[v] = relu(dnorm[v]*(hs[v] + sum_{e:dst=v} hs[src_e]) + b)
// CSR built via dst-bucket binning (chunk-local counting sort in LDS ->
// run-coalesced entry writes) + per-bucket LDS sort -> coalesced CSR.
// Aggregation: one wave per node, lane = channel.
// Requires N <= 131072 (src fits 17 bits).

#define F_IN 256
#define HDIM 64
#define BR_SHIFT 7
#define BRANGE 128
#define BCAP 4608
#define CHUNK 4096
#define NBK 788

typedef short short8 __attribute__((ext_vector_type(8)));
typedef short short4v __attribute__((ext_vector_type(4)));
typedef float float4v __attribute__((ext_vector_type(4)));

__device__ __forceinline__ unsigned bf16_rn(float f) {
  unsigned u = __builtin_bit_cast(unsigned, f);
  return (u + 0x7FFFu + ((u >> 16) & 1u)) >> 16;
}
__device__ __forceinline__ float bf16_to_f32(unsigned h) {
  return __builtin_bit_cast(float, h << 16);
}

// ---------------- binning: chunk-local counting sort ----------------
__global__ __launch_bounds__(256) void bin_kernel(
    const int* __restrict__ src, const int* __restrict__ dst,
    int* __restrict__ deg, int* __restrict__ gcur,
    int* __restrict__ entries, int E, int nb) {
  __shared__ int out32[CHUNK];     // 16 KB: chunk sorted by bucket
  __shared__ int hist[NBK];
  __shared__ int pref[NBK + 1];
  __shared__ int cur[NBK];
  __shared__ int gbase[NBK];
  __shared__ int sscan[256];
  const int tid = threadIdx.x;
  for (int i = tid; i < nb; i += 256) { hist[i] = 0; cur[i] = 0; }
  __syncthreads();
  long e0 = (long)blockIdx.x * CHUNK;
  int cnt = (int)min((long)CHUNK, (long)E - e0);
  // pass 1: bucket histogram + degree count
  for (int i = tid; i < cnt; i += 256) {
    int d = dst[e0 + i];
    atomicAdd(&deg[d], 1);
    atomicAdd(&hist[d >> BR_SHIFT], 1);
  }
  __syncthreads();
  // prefix over nb buckets (thread t owns 4) + reserve global slots
  int b0 = tid * 4;
  int h[4];
  int s = 0;
#pragma unroll
  for (int i = 0; i < 4; ++i) {
    h[i] = (b0 + i < nb) ? hist[b0 + i] : 0;
    s += h[i];
  }
  int x = s;
  sscan[tid] = x;
  __syncthreads();
  for (int off = 1; off < 256; off <<= 1) {
    int t = (tid >= off) ? sscan[tid - off] : 0;
    __syncthreads();
    sscan[tid] += t;
    __syncthreads();
  }
  int run = sscan[tid] - x;   // exclusive prefix
#pragma unroll
  for (int i = 0; i < 4; ++i) {
    if (b0 + i < nb) {
      pref[b0 + i] = run;
      if (h[i] > 0) gbase[b0 + i] = atomicAdd(&gcur[b0 + i], h[i]);
      run += h[i];
    }
  }
  if (tid == 0) pref[nb] = cnt;
  __syncthreads();
  // pass 2: rank + place into sorted LDS position
  for (int i = tid; i < cnt; i += 256) {
    int d = dst[e0 + i];
    int sv = src[e0 + i];
    int b = d >> BR_SHIFT;
    int r = atomicAdd(&cur[b], 1);
    out32[pref[b] + r] = ((d & (BRANGE - 1)) << 17) | sv;
  }
  __syncthreads();
  // pass 3: write sorted chunk; consecutive j -> consecutive global slots
  float inv = (float)nb / (float)cnt;
  for (int j = tid; j < cnt; j += 256) {
    int b = min((int)((float)j * inv), nb - 1);
    while (pref[b] > j) --b;
    while (pref[b + 1] <= j) ++b;
    int slot = gbase[b] + (j - pref[b]);
    if (slot < BCAP) entries[(size_t)b * BCAP + slot] = out32[j];
  }
}

// ---------------- rowptr scan ----------------
__global__ __launch_bounds__(256) void block_sum_kernel(
    const int* __restrict__ counts, int* __restrict__ bs, int N) {
  __shared__ int s[256];
  int b = blockIdx.x, tid = threadIdx.x;
  int base = b * 1024 + tid * 4;
  int sum = 0;
#pragma unroll
  for (int i = 0; i < 4; ++i) if (base + i < N) sum += counts[base + i];
  s[tid] = sum;
  __syncthreads();
  for (int off = 128; off > 0; off >>= 1) {
    if (tid < off) s[tid] += s[tid + off];
    __syncthreads();
  }
  if (tid == 0) bs[b] = s[0];
}

__global__ __launch_bounds__(256) void scan_blocksums_kernel(
    int* __restrict__ bs, int nb, int* __restrict__ rowptr, int N, int E) {
  __shared__ int s[256];
  int tid = threadIdx.x;
  int x = (tid < nb) ? bs[tid] : 0;
  s[tid] = x;
  __syncthreads();
  for (int off = 1; off < 256; off <<= 1) {
    int t = (tid >= off) ? s[tid - off] : 0;
    __syncthreads();
    s[tid] += t;
    __syncthreads();
  }
  if (tid < nb) bs[tid] = s[tid] - x;
  if (tid == 0) rowptr[N] = E;
}

__global__ __launch_bounds__(256) void scan_final_kernel(
    const int* __restrict__ counts, const int* __restrict__ bs,
    int* __restrict__ rowptr, float* __restrict__ dnorm, int N) {
  __shared__ int s[256];
  int b = blockIdx.x, tid = threadIdx.x;
  int base = b * 1024 + tid * 4;
  int c[4];
  int sum = 0;
#pragma unroll
  for (int i = 0; i < 4; ++i) {
    c[i] = (base + i < N) ? counts[base + i] : 0;
    sum += c[i];
  }
  int x = sum;
  s[tid] = x;
  __syncthreads();
  for (int off = 1; off < 256; off <<= 1) {
    int t = (tid >= off) ? s[tid - off] : 0;
    __syncthreads();
    s[tid] += t;
    __syncthreads();
  }
  int off0 = bs[b] + s[tid] - x;
#pragma unroll
  for (int i = 0; i < 4; ++i) {
    if (base + i < N) {
      rowptr[base + i] = off0;
      dnorm[base + i] = rsqrtf((float)c[i] + 1.0f);
      off0 += c[i];
    }
  }
}

// ---------------- per-bucket LDS sort -> coalesced CSR ----------
__global__ __launch_bounds__(256) void csr_build_kernel(
    const int* __restrict__ entries, const int* __restrict__ gcur,
    const int* __restrict__ rowptr, int* __restrict__ csr, int N) {
  __shared__ int lbuf[BCAP];
  __shared__ int lrow[BRANGE];
  __shared__ int lcur[BRANGE];
  const int b = blockIdx.x, tid = threadIdx.x;
  const int v0 = b * BRANGE;
  const int nloc = min(BRANGE, N - v0);
  for (int i = tid; i < nloc; i += 256) {
    lrow[i] = rowptr[v0 + i];
    lcur[i] = 0;
  }
  __syncthreads();
  const int base = lrow[0];
  const int cnt = min(gcur[b], BCAP);
  const int* ep = entries + (size_t)b * BCAP;
  for (int i = tid; i < cnt; i += 256) {
    int e = ep[i];
    int dl = e >> 17;
    int pos = lrow[dl] - base + atomicAdd(&lcur[dl], 1);
    if (pos < BCAP) lbuf[pos] = e & 0x1FFFF;
  }
  __syncthreads();
  int* outp = csr + base;
  for (int i = tid; i < cnt; i += 256) outp[i] = lbuf[i];
}

// ---------------- W -> MFMA B-fragment order, bf16 hi/lo ----------------
template <int K>
__global__ __launch_bounds__(256) void wfrag_kernel(
    const float* __restrict__ W, short* __restrict__ whi,
    short* __restrict__ wlo) {
  constexpr int KS = K / 32;
  int slot = blockIdx.x * 256 + threadIdx.x;
  if (slot >= 4 * KS * 64 * 8) return;
  int j = slot & 7;
  int lane = (slot >> 3) & 63;
  int fk = slot >> 9;
  int ks = fk % KS;
  int ct = fk / KS;
  int k = ks * 32 + (lane >> 4) * 8 + j;
  int n = ct * 16 + (lane & 15);
  float w = W[k * 64 + n];
  unsigned h = bf16_rn(w);
  unsigned l = bf16_rn(w - bf16_to_f32(h));
  whi[slot] = (short)h;
  wlo[slot] = (short)l;
}

// ---------------- MFMA GEMM: out[N,64] = (X[N,K]@W)*dnorm[row] ----------
template <int K>
__global__ __launch_bounds__(512) void mfma_gemm_kernel(
    const float* __restrict__ X, const short* __restrict__ whi,
    const short* __restrict__ wlo, const float* __restrict__ dnorm,
    float* __restrict__ out, int N) {
  constexpr int KS = K / 32;
  constexpr int P = K + 8;
  __shared__ __align__(16) short Ahi[64 * P];
  __shared__ __align__(16) short Alo[64 * P];
  const int tid = threadIdx.x;
  const long base = (long)blockIdx.x * 64;
  constexpr int C4 = K / 4;
  constexpr int NL = 64 * C4 / 512;
#pragma unroll
  for (int i = 0; i < NL; ++i) {
    int idx = tid + i * 512;
    int row = idx / C4;
    int c4 = idx % C4;
    long r = base + row;
    if (r >= N) r = N - 1;
    float4v v = *(const float4v*)&X[(size_t)r * K + c4 * 4];
    short4v hv, lv;
#pragma unroll
    for (int j = 0; j < 4; ++j) {
      float f = v[j];
      unsigned h = bf16_rn(f);
      unsigned l = bf16_rn(f - bf16_to_f32(h));
      hv[j] = (short)h;
      lv[j] = (short)l;
    }
    *(short4v*)&Ahi[row * P + c4 * 4] = hv;
    *(short4v*)&Alo[row * P + c4 * 4] = lv;
  }
  __syncthreads();
  const int lane = tid & 63;
  const int wave = tid >> 6;
  const int rt = wave & 3;
  const int chalf = wave >> 2;
  const int m = lane & 15;
  const int q = lane >> 4;
  const int arow = rt * 16 + m;
  float4v acc[2];
  acc[0] = (float4v){0.f, 0.f, 0.f, 0.f};
  acc[1] = (float4v){0.f, 0.f, 0.f, 0.f};
  for (int ks = 0; ks < KS; ++ks) {
    int koff = ks * 32 + q * 8;
    short8 ah = *(const short8*)&Ahi[arow * P + koff];
    short8 al = *(const short8*)&Alo[arow * P + koff];
#pragma unroll
    for (int cc = 0; cc < 2; ++cc) {
      int ct = chalf * 2 + cc;
      size_t fo = ((size_t)(ct * KS + ks) * 64 + lane) * 8;
      short8 bh = *(const short8*)&whi[fo];
      short8 bl = *(const short8*)&wlo[fo];
      acc[cc] = __builtin_amdgcn_mfma_f32_16x16x32_bf16(ah, bh, acc[cc], 0, 0, 0);
      acc[cc] = __builtin_amdgcn_mfma_f32_16x16x32_bf16(ah, bl, acc[cc], 0, 0, 0);
      acc[cc] = __builtin_amdgcn_mfma_f32_16x16x32_bf16(al, bh, acc[cc], 0, 0, 0);
    }
  }
#pragma unroll
  for (int reg = 0; reg < 4; ++reg) {
    long grow = base + rt * 16 + q * 4 + reg;
    if (grow < N) {
      float dn = dnorm[grow];
#pragma unroll
      for (int cc = 0; cc < 2; ++cc) {
        int ct = chalf * 2 + cc;
        out[grow * 64 + ct * 16 + m] = acc[cc][reg] * dn;
      }
    }
  }
}

// ---------------- Gather aggregation: one wave per node ----------------
__global__ __launch_bounds__(256) void gather_agg_kernel(
    const float* __restrict__ hs, const int* __restrict__ rowptr,
    const int* __restrict__ csr, const float* __restrict__ dnorm,
    const float* __restrict__ bias, float* __restrict__ hout, int N) {
  const int lane = threadIdx.x & 63;
  const int wave = __builtin_amdgcn_readfirstlane((int)(threadIdx.x >> 6));
  int v = blockIdx.x * 4 + wave;
  if (v >= N) return;
  int beg = rowptr[v], end = rowptr[v + 1];
  float a0 = hs[(size_t)v * 64 + lane], a1 = 0.f, a2 = 0.f, a3 = 0.f;
  int j = beg;
  for (; j + 4 <= end; j += 4) {
    int s0 = csr[j], s1 = csr[j + 1], s2 = csr[j + 2], s3 = csr[j + 3];
    a0 += hs[(size_t)s0 * 64 + lane];
    a1 += hs[(size_t)s1 * 64 + lane];
    a2 += hs[(size_t)s2 * 64 + lane];
    a3 += hs[(size_t)s3 * 64 + lane];
  }
  for (; j < end; ++j) a0 += hs[(size_t)csr[j] * 64 + lane];
  float val = dnorm[v] * ((a0 + a1) + (a2 + a3)) + bias[lane];
  hout[(size_t)v * 64 + lane] = fmaxf(val, 0.f);
}

__global__ __launch_bounds__(256) void gather_agg_pool_kernel(
    const float* __restrict__ hs, const int* __restrict__ rowptr,
    const int* __restrict__ csr, const float* __restrict__ dnorm,
    const float* __restrict__ bias, const int* __restrict__ batch,
    float* __restrict__ pooled, int N) {
  const int lane = threadIdx.x & 63;
  const int wave = __builtin_amdgcn_readfirstlane((int)(threadIdx.x >> 6));
  int v = blockIdx.x * 4 + wave;
  if (v >= N) return;
  int beg = rowptr[v], end = rowptr[v + 1];
  float a0 = hs[(size_t)v * 64 + lane], a1 = 0.f, a2 = 0.f, a3 = 0.f;
  int j = beg;
  for (; j + 4 <= end; j += 4) {
    int s0 = csr[j], s1 = csr[j + 1], s2 = csr[j + 2], s3 = csr[j + 3];
    a0 += hs[(size_t)s0 * 64 + lane];
    a1 += hs[(size_t)s1 * 64 + lane];
    a2 += hs[(size_t)s2 * 64 + lane];
    a3 += hs[(size_t)s3 * 64 + lane];
  }
  for (; j < end; ++j) a0 += hs[(size_t)csr[j] * 64 + lane];
  float val = dnorm[v] * ((a0 + a1) + (a2 + a3)) + bias[lane];
  val = fmaxf(val, 0.f);
  atomicAdd(&pooled[(size_t)batch[v] * 64 + lane], val);
}

// ---------------- Final FC ----------------
__global__ __launch_bounds__(256) void final_fc_kernel(
    const float* __restrict__ pooled, const int* __restrict__ batch,
    const float* __restrict__ fcW, const float* __restrict__ fcb,
    float* __restrict__ out, int G, int N) {
  int t = blockIdx.x * 256 + threadIdx.x;
  if (t < G * 2) {
    int g = t >> 1, c = t & 1;
    int lo = 0, hi = N;
    while (lo < hi) { int m = (lo + hi) >> 1; if (batch[m] < g) lo = m + 1; else hi = m; }
    int lb = lo;
    lo = 0; hi = N;
    while (lo < hi) { int m = (lo + hi) >> 1; if (batch[m] <= g) lo = m + 1; else hi = m; }
    int cntg = lo - lb;
    float inv = 1.0f / fmaxf((float)cntg, 1.0f);
    float acc = fcb[c];
#pragma unroll
    for (int h = 0; h < 64; ++h)
      acc = fmaf(pooled[g * 64 + h] * inv, fcW[h * 2 + c], acc);
    out[t] = acc;
  }
}

extern "C" void kernel_launch(void* const* d_in, const int* in_sizes, int n_in,
                              void* d_out, int out_size, void* d_ws, size_t ws_size,
                              hipStream_t stream) {
  const float* x   = (const float*)d_in[0];
  const int*   ei  = (const int*)d_in[1];
  const int*   bat = (const int*)d_in[2];
  const float* W1  = (const float*)d_in[3];
  const float* b1  = (const float*)d_in[4];
  const float* W2  = (const float*)d_in[5];
  const float* b2  = (const float*)d_in[6];
  const float* fcW = (const float*)d_in[7];
  const float* fcb = (const float*)d_in[8];
  float* out = (float*)d_out;

  const int N = in_sizes[0] / F_IN;      // 100000
  const int E = in_sizes[1] / 2;         // 3200000
  const int G = out_size / 2;            // 128
  const int* src = ei;
  const int* dst = ei + E;
  const int nb  = (N + BRANGE - 1) >> BR_SHIFT;   // 782 buckets
  const int nsc = (N + 1023) / 1024;              // 98 scan chunks

  auto aln = [](size_t v) { return (v + 63) & ~(size_t)63; };
  char* w = (char*)d_ws;
  int*   entries = (int*)w;     w += aln((size_t)nb * BCAP * 4);
  int*   gcur    = (int*)w;     w += aln((size_t)nb * 4);
  int*   deg     = (int*)w;     w += aln((size_t)N * 4);
  int*   rowptr  = (int*)w;     w += aln((size_t)(N + 1) * 4);
  int*   bs      = (int*)w;     w += 1024;
  float* dnorm   = (float*)w;   w += aln((size_t)N * 4);
  int*   csr     = (int*)w;     w += aln((size_t)E * 4);
  float* hs      = (float*)w;   w += aln((size_t)N * 64 * 4);
  float* h1      = (float*)w;   w += aln((size_t)N * 64 * 4);
  float* pooled  = (float*)w;   w += aln((size_t)G * 64 * 4);
  short* whi1    = (short*)w;   w += aln((size_t)F_IN * 64 * 2);
  short* wlo1    = (short*)w;   w += aln((size_t)F_IN * 64 * 2);
  short* whi2    = (short*)w;   w += aln((size_t)HDIM * 64 * 2);
  short* wlo2    = (short*)w;   w += aln((size_t)HDIM * 64 * 2);

  hipMemsetAsync(deg, 0, (size_t)N * 4, stream);
  hipMemsetAsync(gcur, 0, (size_t)nb * 4, stream);
  hipMemsetAsync(pooled, 0, (size_t)G * 64 * 4, stream);

  // W fragment prep
  wfrag_kernel<F_IN><<<(F_IN * 64 * 8 / 8 + 255) / 256, 256, 0, stream>>>(W1, whi1, wlo1);
  wfrag_kernel<HDIM><<<(HDIM * 64 * 8 / 8 + 255) / 256, 256, 0, stream>>>(W2, whi2, wlo2);

  // CSR build: bin (counting sort) -> scan -> bucket-local sort
  bin_kernel<<<(E + CHUNK - 1) / CHUNK, 256, 0, stream>>>(
      src, dst, deg, gcur, entries, E, nb);
  block_sum_kernel<<<nsc, 256, 0, stream>>>(deg, bs, N);
  scan_blocksums_kernel<<<1, 256, 0, stream>>>(bs, nsc, rowptr, N, E);
  scan_final_kernel<<<nsc, 256, 0, stream>>>(deg, bs, rowptr, dnorm, N);
  csr_build_kernel<<<nb, 256, 0, stream>>>(entries, gcur, rowptr, csr, N);

  // layer 1
  mfma_gemm_kernel<F_IN><<<(N + 63) / 64, 512, 0, stream>>>(x, whi1, wlo1, dnorm, hs, N);
  gather_agg_kernel<<<(N + 3) / 4, 256, 0, stream>>>(hs, rowptr, csr, dnorm, b1, h1, N);

  // layer 2 (epilogue fused with pooling)
  mfma_gemm_kernel<HDIM><<<(N + 63) / 64, 512, 0, stream>>>(h1, W2 ? whi2 : whi2, wlo2, dnorm, hs, N);
  gather_agg_pool_kernel<<<(N + 3) / 4, 256, 0, stream>>>(hs, rowptr, csr, dnorm, b2, bat, pooled, N);

  // FC
  final_fc_kernel<<<1, 256, 0, stream>>>(pooled, bat, fcW, fcb, out, G, N);
}

// Round 7
// 645.754 us; speedup vs baseline: 1.0831x; 1.0831x over previous
//
#include <hip/hip_runtime.h>
#include <hip/hip_bf16.h>

// GCN forward, CSR gather + MFMA GEMMs (bf16 hi/lo split for f32 accuracy):
//   hs = (X@W) * dnorm[v]
//   h_out[v] = relu(dnorm[v]*(hs[v] + sum_{e:dst=v} hs[src_e]) + b)
// CSR build: (1) bin = chunk-local counting sort by 128-node dst-bucket
// (NO per-edge deg atomics — degrees recovered per-bucket in csr_build),
// (2) tiny scan over bucket counts, (3) csr_build: histogram + local prefix
// -> rowptr/dnorm + sorted CSR segment, all coalesced.
// Aggregation: one wave per node, lane = channel.
// Requires N <= 131072 (src fits 17 bits).

#define F_IN 256
#define HDIM 64
#define BR_SHIFT 7
#define BRANGE 128
#define BCAP 4608
#define CHUNK 8192
#define NBK 788

typedef short short8 __attribute__((ext_vector_type(8)));
typedef short short4v __attribute__((ext_vector_type(4)));
typedef float float4v __attribute__((ext_vector_type(4)));

__device__ __forceinline__ unsigned bf16_rn(float f) {
  unsigned u = __builtin_bit_cast(unsigned, f);
  return (u + 0x7FFFu + ((u >> 16) & 1u)) >> 16;
}
__device__ __forceinline__ float bf16_to_f32(unsigned h) {
  return __builtin_bit_cast(float, h << 16);
}

// ---------------- binning: chunk-local counting sort (no deg atomics) ------
__global__ __launch_bounds__(256) void bin_kernel(
    const int* __restrict__ src, const int* __restrict__ dst,
    int* __restrict__ gcur, int* __restrict__ entries, int E, int nb) {
  __shared__ int out32[CHUNK];      // 32 KB: chunk sorted by bucket
  __shared__ int pref[NBK + 1];
  __shared__ int cur[NBK];
  __shared__ int gbase[NBK];
  __shared__ int sscan[256];
  const int tid = threadIdx.x;
  for (int i = tid; i < nb; i += 256) cur[i] = 0;
  __syncthreads();
  long e0 = (long)blockIdx.x * CHUNK;
  int cnt = (int)min((long)CHUNK, (long)E - e0);
  // pass 1: bucket histogram (into cur)
  for (int i = tid; i < cnt; i += 256)
    atomicAdd(&cur[dst[e0 + i] >> BR_SHIFT], 1);
  __syncthreads();
  // prefix over nb buckets (thread owns 4) + reserve global slots
  int b0 = tid * 4;
  int h[4];
  int s = 0;
#pragma unroll
  for (int i = 0; i < 4; ++i) {
    h[i] = (b0 + i < nb) ? cur[b0 + i] : 0;
    s += h[i];
  }
  int x = s;
  sscan[tid] = x;
  __syncthreads();
  for (int off = 1; off < 256; off <<= 1) {
    int t = (tid >= off) ? sscan[tid - off] : 0;
    __syncthreads();
    sscan[tid] += t;
    __syncthreads();
  }
  int run = sscan[tid] - x;   // exclusive prefix
#pragma unroll
  for (int i = 0; i < 4; ++i) {
    if (b0 + i < nb) {
      pref[b0 + i] = run;
      cur[b0 + i] = run;      // running cursor starts at local prefix
      if (h[i] > 0) gbase[b0 + i] = atomicAdd(&gcur[b0 + i], h[i]);
      run += h[i];
    }
  }
  if (tid == 0) pref[nb] = cnt;
  __syncthreads();
  // pass 2: place into bucket-sorted LDS position
  for (int i = tid; i < cnt; i += 256) {
    int d = dst[e0 + i];
    int sv = src[e0 + i];
    int b = d >> BR_SHIFT;
    int r = atomicAdd(&cur[b], 1);
    out32[r] = ((d & (BRANGE - 1)) << 17) | sv;
  }
  __syncthreads();
  // pass 3: write sorted chunk; consecutive j in a bucket -> consecutive slots
  for (int j = tid; j < cnt; j += 256) {
    int lo = 0, hi = nb - 1;
    while (lo < hi) {
      int mid = (lo + hi + 1) >> 1;
      if (pref[mid] <= j) lo = mid; else hi = mid - 1;
    }
    int b = lo;
    int slot = gbase[b] + (j - pref[b]);
    if (slot < BCAP) entries[(size_t)b * BCAP + slot] = out32[j];
  }
}

// ---------------- tiny scan over bucket counts -> bucket bases ----------
__global__ __launch_bounds__(256) void bucket_scan_kernel(
    const int* __restrict__ gcur, int* __restrict__ bbase,
    int* __restrict__ rowptr, int nb, int N, int E) {
  __shared__ int sscan[256];
  const int tid = threadIdx.x;
  int b0 = tid * 4;
  int h[4];
  int s = 0;
#pragma unroll
  for (int i = 0; i < 4; ++i) {
    h[i] = (b0 + i < nb) ? min(gcur[b0 + i], BCAP) : 0;
    s += h[i];
  }
  int x = s;
  sscan[tid] = x;
  __syncthreads();
  for (int off = 1; off < 256; off <<= 1) {
    int t = (tid >= off) ? sscan[tid - off] : 0;
    __syncthreads();
    sscan[tid] += t;
    __syncthreads();
  }
  int run = sscan[tid] - x;
#pragma unroll
  for (int i = 0; i < 4; ++i) {
    if (b0 + i < nb) {
      bbase[b0 + i] = run;
      run += h[i];
    }
  }
  if (tid == 0) rowptr[N] = E;
}

// ---------------- csr_build: histogram + prefix + sort, writes rowptr/dnorm
__global__ __launch_bounds__(256) void csr_build_kernel(
    const int* __restrict__ entries, const int* __restrict__ gcur,
    const int* __restrict__ bbase, int* __restrict__ rowptr,
    float* __restrict__ dnorm, int* __restrict__ csr, int N) {
  __shared__ int lbuf[BCAP];
  __shared__ int lcnt[BRANGE];
  __shared__ int lpref[BRANGE];
  __shared__ int lcur[BRANGE];
  const int b = blockIdx.x, tid = threadIdx.x;
  const int v0 = b * BRANGE;
  const int nloc = min(BRANGE, N - v0);
  if (tid < BRANGE) lcnt[tid] = 0;
  __syncthreads();
  const int cnt = min(gcur[b], BCAP);
  const int base = bbase[b];
  const int* ep = entries + (size_t)b * BCAP;
  for (int i = tid; i < cnt; i += 256) atomicAdd(&lcnt[ep[i] >> 17], 1);
  __syncthreads();
  if (tid < BRANGE) lpref[tid] = lcnt[tid];
  __syncthreads();
  for (int off = 1; off < BRANGE; off <<= 1) {
    int t = 0;
    if (tid < BRANGE && tid >= off) t = lpref[tid - off];
    __syncthreads();
    if (tid < BRANGE) lpref[tid] += t;
    __syncthreads();
  }
  if (tid < BRANGE) {
    int excl = lpref[tid] - lcnt[tid];
    lcur[tid] = excl;
    if (tid < nloc) {
      rowptr[v0 + tid] = base + excl;
      dnorm[v0 + tid] = rsqrtf((float)lcnt[tid] + 1.0f);
    }
  }
  __syncthreads();
  for (int i = tid; i < cnt; i += 256) {
    int e = ep[i];
    int dl = e >> 17;
    int pos = atomicAdd(&lcur[dl], 1);
    if (pos < BCAP) lbuf[pos] = e & 0x1FFFF;
  }
  __syncthreads();
  int* outp = csr + base;
  for (int i = tid; i < cnt; i += 256) outp[i] = lbuf[i];
}

// ---------------- W -> MFMA B-fragment order, bf16 hi/lo ----------------
template <int K>
__global__ __launch_bounds__(256) void wfrag_kernel(
    const float* __restrict__ W, short* __restrict__ whi,
    short* __restrict__ wlo) {
  constexpr int KS = K / 32;
  int slot = blockIdx.x * 256 + threadIdx.x;
  if (slot >= 4 * KS * 64 * 8) return;
  int j = slot & 7;
  int lane = (slot >> 3) & 63;
  int fk = slot >> 9;
  int ks = fk % KS;
  int ct = fk / KS;
  int k = ks * 32 + (lane >> 4) * 8 + j;
  int n = ct * 16 + (lane & 15);
  float w = W[k * 64 + n];
  unsigned h = bf16_rn(w);
  unsigned l = bf16_rn(w - bf16_to_f32(h));
  whi[slot] = (short)h;
  wlo[slot] = (short)l;
}

// ---------------- MFMA GEMM: out[N,64] = (X[N,K]@W)*dnorm[row] ----------
template <int K>
__global__ __launch_bounds__(512) void mfma_gemm_kernel(
    const float* __restrict__ X, const short* __restrict__ whi,
    const short* __restrict__ wlo, const float* __restrict__ dnorm,
    float* __restrict__ out, int N) {
  constexpr int KS = K / 32;
  constexpr int P = K + 8;
  __shared__ __align__(16) short Ahi[64 * P];
  __shared__ __align__(16) short Alo[64 * P];
  const int tid = threadIdx.x;
  const long base = (long)blockIdx.x * 64;
  constexpr int C4 = K / 4;
  constexpr int NL = 64 * C4 / 512;
#pragma unroll
  for (int i = 0; i < NL; ++i) {
    int idx = tid + i * 512;
    int row = idx / C4;
    int c4 = idx % C4;
    long r = base + row;
    if (r >= N) r = N - 1;
    float4v v = *(const float4v*)&X[(size_t)r * K + c4 * 4];
    short4v hv, lv;
#pragma unroll
    for (int j = 0; j < 4; ++j) {
      float f = v[j];
      unsigned h = bf16_rn(f);
      unsigned l = bf16_rn(f - bf16_to_f32(h));
      hv[j] = (short)h;
      lv[j] = (short)l;
    }
    *(short4v*)&Ahi[row * P + c4 * 4] = hv;
    *(short4v*)&Alo[row * P + c4 * 4] = lv;
  }
  __syncthreads();
  const int lane = tid & 63;
  const int wave = tid >> 6;
  const int rt = wave & 3;
  const int chalf = wave >> 2;
  const int m = lane & 15;
  const int q = lane >> 4;
  const int arow = rt * 16 + m;
  float4v acc[2];
  acc[0] = (float4v){0.f, 0.f, 0.f, 0.f};
  acc[1] = (float4v){0.f, 0.f, 0.f, 0.f};
  for (int ks = 0; ks < KS; ++ks) {
    int koff = ks * 32 + q * 8;
    short8 ah = *(const short8*)&Ahi[arow * P + koff];
    short8 al = *(const short8*)&Alo[arow * P + koff];
#pragma unroll
    for (int cc = 0; cc < 2; ++cc) {
      int ct = chalf * 2 + cc;
      size_t fo = ((size_t)(ct * KS + ks) * 64 + lane) * 8;
      short8 bh = *(const short8*)&whi[fo];
      short8 bl = *(const short8*)&wlo[fo];
      acc[cc] = __builtin_amdgcn_mfma_f32_16x16x32_bf16(ah, bh, acc[cc], 0, 0, 0);
      acc[cc] = __builtin_amdgcn_mfma_f32_16x16x32_bf16(ah, bl, acc[cc], 0, 0, 0);
      acc[cc] = __builtin_amdgcn_mfma_f32_16x16x32_bf16(al, bh, acc[cc], 0, 0, 0);
    }
  }
#pragma unroll
  for (int reg = 0; reg < 4; ++reg) {
    long grow = base + rt * 16 + q * 4 + reg;
    if (grow < N) {
      float dn = dnorm[grow];
#pragma unroll
      for (int cc = 0; cc < 2; ++cc) {
        int ct = chalf * 2 + cc;
        out[grow * 64 + ct * 16 + m] = acc[cc][reg] * dn;
      }
    }
  }
}

// ---------------- Gather aggregation: one wave per node ----------------
__global__ __launch_bounds__(256) void gather_agg_kernel(
    const float* __restrict__ hs, const int* __restrict__ rowptr,
    const int* __restrict__ csr, const float* __restrict__ dnorm,
    const float* __restrict__ bias, float* __restrict__ hout, int N) {
  const int lane = threadIdx.x & 63;
  const int wave = __builtin_amdgcn_readfirstlane((int)(threadIdx.x >> 6));
  int v = blockIdx.x * 4 + wave;
  if (v >= N) return;
  int beg = rowptr[v], end = rowptr[v + 1];
  float a0 = hs[(size_t)v * 64 + lane], a1 = 0.f, a2 = 0.f, a3 = 0.f;
  int j = beg;
  for (; j + 4 <= end; j += 4) {
    int s0 = csr[j], s1 = csr[j + 1], s2 = csr[j + 2], s3 = csr[j + 3];
    a0 += hs[(size_t)s0 * 64 + lane];
    a1 += hs[(size_t)s1 * 64 + lane];
    a2 += hs[(size_t)s2 * 64 + lane];
    a3 += hs[(size_t)s3 * 64 + lane];
  }
  for (; j < end; ++j) a0 += hs[(size_t)csr[j] * 64 + lane];
  float val = dnorm[v] * ((a0 + a1) + (a2 + a3)) + bias[lane];
  hout[(size_t)v * 64 + lane] = fmaxf(val, 0.f);
}

__global__ __launch_bounds__(256) void gather_agg_pool_kernel(
    const float* __restrict__ hs, const int* __restrict__ rowptr,
    const int* __restrict__ csr, const float* __restrict__ dnorm,
    const float* __restrict__ bias, const int* __restrict__ batch,
    float* __restrict__ pooled, int N) {
  const int lane = threadIdx.x & 63;
  const int wave = __builtin_amdgcn_readfirstlane((int)(threadIdx.x >> 6));
  int v = blockIdx.x * 4 + wave;
  if (v >= N) return;
  int beg = rowptr[v], end = rowptr[v + 1];
  float a0 = hs[(size_t)v * 64 + lane], a1 = 0.f, a2 = 0.f, a3 = 0.f;
  int j = beg;
  for (; j + 4 <= end; j += 4) {
    int s0 = csr[j], s1 = csr[j + 1], s2 = csr[j + 2], s3 = csr[j + 3];
    a0 += hs[(size_t)s0 * 64 + lane];
    a1 += hs[(size_t)s1 * 64 + lane];
    a2 += hs[(size_t)s2 * 64 + lane];
    a3 += hs[(size_t)s3 * 64 + lane];
  }
  for (; j < end; ++j) a0 += hs[(size_t)csr[j] * 64 + lane];
  float val = dnorm[v] * ((a0 + a1) + (a2 + a3)) + bias[lane];
  val = fmaxf(val, 0.f);
  atomicAdd(&pooled[(size_t)batch[v] * 64 + lane], val);
}

// ---------------- Final FC ----------------
__global__ __launch_bounds__(256) void final_fc_kernel(
    const float* __restrict__ pooled, const int* __restrict__ batch,
    const float* __restrict__ fcW, const float* __restrict__ fcb,
    float* __restrict__ out, int G, int N) {
  int t = blockIdx.x * 256 + threadIdx.x;
  if (t < G * 2) {
    int g = t >> 1, c = t & 1;
    int lo = 0, hi = N;
    while (lo < hi) { int m = (lo + hi) >> 1; if (batch[m] < g) lo = m + 1; else hi = m; }
    int lb = lo;
    lo = 0; hi = N;
    while (lo < hi) { int m = (lo + hi) >> 1; if (batch[m] <= g) lo = m + 1; else hi = m; }
    int cntg = lo - lb;
    float inv = 1.0f / fmaxf((float)cntg, 1.0f);
    float acc = fcb[c];
#pragma unroll
    for (int h = 0; h < 64; ++h)
      acc = fmaf(pooled[g * 64 + h] * inv, fcW[h * 2 + c], acc);
    out[t] = acc;
  }
}

extern "C" void kernel_launch(void* const* d_in, const int* in_sizes, int n_in,
                              void* d_out, int out_size, void* d_ws, size_t ws_size,
                              hipStream_t stream) {
  const float* x   = (const float*)d_in[0];
  const int*   ei  = (const int*)d_in[1];
  const int*   bat = (const int*)d_in[2];
  const float* W1  = (const float*)d_in[3];
  const float* b1  = (const float*)d_in[4];
  const float* W2  = (const float*)d_in[5];
  const float* b2  = (const float*)d_in[6];
  const float* fcW = (const float*)d_in[7];
  const float* fcb = (const float*)d_in[8];
  float* out = (float*)d_out;

  const int N = in_sizes[0] / F_IN;      // 100000
  const int E = in_sizes[1] / 2;         // 3200000
  const int G = out_size / 2;            // 128
  const int* src = ei;
  const int* dst = ei + E;
  const int nb  = (N + BRANGE - 1) >> BR_SHIFT;   // 782 buckets

  auto aln = [](size_t v) { return (v + 63) & ~(size_t)63; };
  char* w = (char*)d_ws;
  int*   entries = (int*)w;     w += aln((size_t)nb * BCAP * 4);
  int*   gcur    = (int*)w;     w += aln((size_t)nb * 4);
  int*   bbase   = (int*)w;     w += aln((size_t)nb * 4);
  int*   rowptr  = (int*)w;     w += aln((size_t)(N + 1) * 4);
  float* dnorm   = (float*)w;   w += aln((size_t)N * 4);
  int*   csr     = (int*)w;     w += aln((size_t)E * 4);
  float* hs      = (float*)w;   w += aln((size_t)N * 64 * 4);
  float* h1      = (float*)w;   w += aln((size_t)N * 64 * 4);
  float* pooled  = (float*)w;   w += aln((size_t)G * 64 * 4);
  short* whi1    = (short*)w;   w += aln((size_t)F_IN * 64 * 2);
  short* wlo1    = (short*)w;   w += aln((size_t)F_IN * 64 * 2);
  short* whi2    = (short*)w;   w += aln((size_t)HDIM * 64 * 2);
  short* wlo2    = (short*)w;   w += aln((size_t)HDIM * 64 * 2);

  hipMemsetAsync(gcur, 0, (size_t)nb * 4, stream);
  hipMemsetAsync(pooled, 0, (size_t)G * 64 * 4, stream);

  // W fragment prep
  wfrag_kernel<F_IN><<<(F_IN * 64 * 8 / 8 + 255) / 256, 256, 0, stream>>>(W1, whi1, wlo1);
  wfrag_kernel<HDIM><<<(HDIM * 64 * 8 / 8 + 255) / 256, 256, 0, stream>>>(W2, whi2, wlo2);

  // CSR build: bin (counting sort, no deg atomics) -> bucket scan -> build
  bin_kernel<<<(E + CHUNK - 1) / CHUNK, 256, 0, stream>>>(
      src, dst, gcur, entries, E, nb);
  bucket_scan_kernel<<<1, 256, 0, stream>>>(gcur, bbase, rowptr, nb, N, E);
  csr_build_kernel<<<nb, 256, 0, stream>>>(entries, gcur, bbase, rowptr,
                                           dnorm, csr, N);

  // layer 1
  mfma_gemm_kernel<F_IN><<<(N + 63) / 64, 512, 0, stream>>>(x, whi1, wlo1, dnorm, hs, N);
  gather_agg_kernel<<<(N + 3) / 4, 256, 0, stream>>>(hs, rowptr, csr, dnorm, b1, h1, N);

  // layer 2 (epilogue fused with pooling)
  mfma_gemm_kernel<HDIM><<<(N + 63) / 64, 512, 0, stream>>>(h1, whi2, wlo2, dnorm, hs, N);
  gather_agg_pool_kernel<<<(N + 3) / 4, 256, 0, stream>>>(hs, rowptr, csr, dnorm, b2, bat, pooled, N);

  // FC
  final_fc_kernel<<<1, 256, 0, stream>>>(pooled, bat, fcW, fcb, out, G, N);
}

// Round 8
// 548.655 us; speedup vs baseline: 1.2748x; 1.1770x over previous
//
#include <hip/hip_runtime.h>
#include <hip/hip_bf16.h>

// GCN forward, CSR gather + MFMA GEMMs (bf16 hi/lo split for f32 accuracy):
//   hs = (X@W) * dnorm[v]        -- stored FP16 (halves gather traffic)
//   h_out[v] = relu(dnorm[v]*(hs[v] + sum_{e:dst=v} hs[src_e]) + b)
// CSR build: bin = chunk-local counting sort by 128-node dst-bucket (no
// per-edge deg atomics), tiny bucket scan, csr_build = per-bucket histogram
// + prefix -> rowptr/dnorm + sorted CSR segment (all coalesced writes).
// Aggregation: one wave per node, lane = channel, f32 accumulate.
// Requires N <= 131072 (src fits 17 bits).

#define F_IN 256
#define HDIM 64
#define BR_SHIFT 7
#define BRANGE 128
#define BCAP 4608
#define CHUNK 8192
#define NBK 788

typedef short short8 __attribute__((ext_vector_type(8)));
typedef short short4v __attribute__((ext_vector_type(4)));
typedef float float4v __attribute__((ext_vector_type(4)));
typedef _Float16 half_t;

__device__ __forceinline__ unsigned bf16_rn(float f) {
  unsigned u = __builtin_bit_cast(unsigned, f);
  return (u + 0x7FFFu + ((u >> 16) & 1u)) >> 16;
}
__device__ __forceinline__ float bf16_to_f32(unsigned h) {
  return __builtin_bit_cast(float, h << 16);
}

// ---------------- binning: chunk-local counting sort (no deg atomics) ------
__global__ __launch_bounds__(256) void bin_kernel(
    const int* __restrict__ src, const int* __restrict__ dst,
    int* __restrict__ gcur, int* __restrict__ entries, int E, int nb) {
  __shared__ int out32[CHUNK];
  __shared__ int pref[NBK + 1];
  __shared__ int cur[NBK];
  __shared__ int gbase[NBK];
  __shared__ int sscan[256];
  const int tid = threadIdx.x;
  for (int i = tid; i < nb; i += 256) cur[i] = 0;
  __syncthreads();
  long e0 = (long)blockIdx.x * CHUNK;
  int cnt = (int)min((long)CHUNK, (long)E - e0);
  for (int i = tid; i < cnt; i += 256)
    atomicAdd(&cur[dst[e0 + i] >> BR_SHIFT], 1);
  __syncthreads();
  int b0 = tid * 4;
  int h[4];
  int s = 0;
#pragma unroll
  for (int i = 0; i < 4; ++i) {
    h[i] = (b0 + i < nb) ? cur[b0 + i] : 0;
    s += h[i];
  }
  int x = s;
  sscan[tid] = x;
  __syncthreads();
  for (int off = 1; off < 256; off <<= 1) {
    int t = (tid >= off) ? sscan[tid - off] : 0;
    __syncthreads();
    sscan[tid] += t;
    __syncthreads();
  }
  int run = sscan[tid] - x;
#pragma unroll
  for (int i = 0; i < 4; ++i) {
    if (b0 + i < nb) {
      pref[b0 + i] = run;
      cur[b0 + i] = run;
      if (h[i] > 0) gbase[b0 + i] = atomicAdd(&gcur[b0 + i], h[i]);
      run += h[i];
    }
  }
  if (tid == 0) pref[nb] = cnt;
  __syncthreads();
  for (int i = tid; i < cnt; i += 256) {
    int d = dst[e0 + i];
    int sv = src[e0 + i];
    int b = d >> BR_SHIFT;
    int r = atomicAdd(&cur[b], 1);
    out32[r] = ((d & (BRANGE - 1)) << 17) | sv;
  }
  __syncthreads();
  for (int j = tid; j < cnt; j += 256) {
    int lo = 0, hi = nb - 1;
    while (lo < hi) {
      int mid = (lo + hi + 1) >> 1;
      if (pref[mid] <= j) lo = mid; else hi = mid - 1;
    }
    int b = lo;
    int slot = gbase[b] + (j - pref[b]);
    if (slot < BCAP) entries[(size_t)b * BCAP + slot] = out32[j];
  }
}

// ---------------- tiny scan over bucket counts -> bucket bases ----------
__global__ __launch_bounds__(256) void bucket_scan_kernel(
    const int* __restrict__ gcur, int* __restrict__ bbase,
    int* __restrict__ rowptr, int nb, int N, int E) {
  __shared__ int sscan[256];
  const int tid = threadIdx.x;
  int b0 = tid * 4;
  int h[4];
  int s = 0;
#pragma unroll
  for (int i = 0; i < 4; ++i) {
    h[i] = (b0 + i < nb) ? min(gcur[b0 + i], BCAP) : 0;
    s += h[i];
  }
  int x = s;
  sscan[tid] = x;
  __syncthreads();
  for (int off = 1; off < 256; off <<= 1) {
    int t = (tid >= off) ? sscan[tid - off] : 0;
    __syncthreads();
    sscan[tid] += t;
    __syncthreads();
  }
  int run = sscan[tid] - x;
#pragma unroll
  for (int i = 0; i < 4; ++i) {
    if (b0 + i < nb) {
      bbase[b0 + i] = run;
      run += h[i];
    }
  }
  if (tid == 0) rowptr[N] = E;
}

// ---------------- csr_build: histogram + prefix + sort, writes rowptr/dnorm
__global__ __launch_bounds__(256) void csr_build_kernel(
    const int* __restrict__ entries, const int* __restrict__ gcur,
    const int* __restrict__ bbase, int* __restrict__ rowptr,
    float* __restrict__ dnorm, int* __restrict__ csr, int N) {
  __shared__ int lbuf[BCAP];
  __shared__ int lcnt[BRANGE];
  __shared__ int lpref[BRANGE];
  __shared__ int lcur[BRANGE];
  const int b = blockIdx.x, tid = threadIdx.x;
  const int v0 = b * BRANGE;
  const int nloc = min(BRANGE, N - v0);
  if (tid < BRANGE) lcnt[tid] = 0;
  __syncthreads();
  const int cnt = min(gcur[b], BCAP);
  const int base = bbase[b];
  const int* ep = entries + (size_t)b * BCAP;
  for (int i = tid; i < cnt; i += 256) atomicAdd(&lcnt[ep[i] >> 17], 1);
  __syncthreads();
  if (tid < BRANGE) lpref[tid] = lcnt[tid];
  __syncthreads();
  for (int off = 1; off < BRANGE; off <<= 1) {
    int t = 0;
    if (tid < BRANGE && tid >= off) t = lpref[tid - off];
    __syncthreads();
    if (tid < BRANGE) lpref[tid] += t;
    __syncthreads();
  }
  if (tid < BRANGE) {
    int excl = lpref[tid] - lcnt[tid];
    lcur[tid] = excl;
    if (tid < nloc) {
      rowptr[v0 + tid] = base + excl;
      dnorm[v0 + tid] = rsqrtf((float)lcnt[tid] + 1.0f);
    }
  }
  __syncthreads();
  for (int i = tid; i < cnt; i += 256) {
    int e = ep[i];
    int dl = e >> 17;
    int pos = atomicAdd(&lcur[dl], 1);
    if (pos < BCAP) lbuf[pos] = e & 0x1FFFF;
  }
  __syncthreads();
  int* outp = csr + base;
  for (int i = tid; i < cnt; i += 256) outp[i] = lbuf[i];
}

// ---------------- W -> MFMA B-fragment order, bf16 hi/lo ----------------
template <int K>
__global__ __launch_bounds__(256) void wfrag_kernel(
    const float* __restrict__ W, short* __restrict__ whi,
    short* __restrict__ wlo) {
  constexpr int KS = K / 32;
  int slot = blockIdx.x * 256 + threadIdx.x;
  if (slot >= 4 * KS * 64 * 8) return;
  int j = slot & 7;
  int lane = (slot >> 3) & 63;
  int fk = slot >> 9;
  int ks = fk % KS;
  int ct = fk / KS;
  int k = ks * 32 + (lane >> 4) * 8 + j;
  int n = ct * 16 + (lane & 15);
  float w = W[k * 64 + n];
  unsigned h = bf16_rn(w);
  unsigned l = bf16_rn(w - bf16_to_f32(h));
  whi[slot] = (short)h;
  wlo[slot] = (short)l;
}

// ---------------- MFMA GEMM: out[N,64] = (X[N,K]@W)*dnorm[row] ----------
// OT = float (h1 path) or _Float16 (hs path).
template <int K, typename OT>
__global__ __launch_bounds__(512) void mfma_gemm_kernel(
    const float* __restrict__ X, const short* __restrict__ whi,
    const short* __restrict__ wlo, const float* __restrict__ dnorm,
    OT* __restrict__ out, int N) {
  constexpr int KS = K / 32;
  constexpr int P = K + 8;
  __shared__ __align__(16) short Ahi[64 * P];
  __shared__ __align__(16) short Alo[64 * P];
  const int tid = threadIdx.x;
  const long base = (long)blockIdx.x * 64;
  constexpr int C4 = K / 4;
  constexpr int NL = 64 * C4 / 512;
#pragma unroll
  for (int i = 0; i < NL; ++i) {
    int idx = tid + i * 512;
    int row = idx / C4;
    int c4 = idx % C4;
    long r = base + row;
    if (r >= N) r = N - 1;
    float4v v = *(const float4v*)&X[(size_t)r * K + c4 * 4];
    short4v hv, lv;
#pragma unroll
    for (int j = 0; j < 4; ++j) {
      float f = v[j];
      unsigned h = bf16_rn(f);
      unsigned l = bf16_rn(f - bf16_to_f32(h));
      hv[j] = (short)h;
      lv[j] = (short)l;
    }
    *(short4v*)&Ahi[row * P + c4 * 4] = hv;
    *(short4v*)&Alo[row * P + c4 * 4] = lv;
  }
  __syncthreads();
  const int lane = tid & 63;
  const int wave = tid >> 6;
  const int rt = wave & 3;
  const int chalf = wave >> 2;
  const int m = lane & 15;
  const int q = lane >> 4;
  const int arow = rt * 16 + m;
  float4v acc[2];
  acc[0] = (float4v){0.f, 0.f, 0.f, 0.f};
  acc[1] = (float4v){0.f, 0.f, 0.f, 0.f};
  for (int ks = 0; ks < KS; ++ks) {
    int koff = ks * 32 + q * 8;
    short8 ah = *(const short8*)&Ahi[arow * P + koff];
    short8 al = *(const short8*)&Alo[arow * P + koff];
#pragma unroll
    for (int cc = 0; cc < 2; ++cc) {
      int ct = chalf * 2 + cc;
      size_t fo = ((size_t)(ct * KS + ks) * 64 + lane) * 8;
      short8 bh = *(const short8*)&whi[fo];
      short8 bl = *(const short8*)&wlo[fo];
      acc[cc] = __builtin_amdgcn_mfma_f32_16x16x32_bf16(ah, bh, acc[cc], 0, 0, 0);
      acc[cc] = __builtin_amdgcn_mfma_f32_16x16x32_bf16(ah, bl, acc[cc], 0, 0, 0);
      acc[cc] = __builtin_amdgcn_mfma_f32_16x16x32_bf16(al, bh, acc[cc], 0, 0, 0);
    }
  }
#pragma unroll
  for (int reg = 0; reg < 4; ++reg) {
    long grow = base + rt * 16 + q * 4 + reg;
    if (grow < N) {
      float dn = dnorm[grow];
#pragma unroll
      for (int cc = 0; cc < 2; ++cc) {
        int ct = chalf * 2 + cc;
        out[grow * 64 + ct * 16 + m] = (OT)(acc[cc][reg] * dn);
      }
    }
  }
}

// ---------------- Gather aggregation: one wave per node, fp16 rows ------
__global__ __launch_bounds__(256) void gather_agg_kernel(
    const half_t* __restrict__ hs, const int* __restrict__ rowptr,
    const int* __restrict__ csr, const float* __restrict__ dnorm,
    const float* __restrict__ bias, float* __restrict__ hout, int N) {
  const int lane = threadIdx.x & 63;
  const int wave = __builtin_amdgcn_readfirstlane((int)(threadIdx.x >> 6));
  int v = blockIdx.x * 4 + wave;
  if (v >= N) return;
  int beg = rowptr[v], end = rowptr[v + 1];
  float a0 = (float)hs[(size_t)v * 64 + lane], a1 = 0.f, a2 = 0.f, a3 = 0.f;
  int j = beg;
  for (; j + 4 <= end; j += 4) {
    int s0 = csr[j], s1 = csr[j + 1], s2 = csr[j + 2], s3 = csr[j + 3];
    a0 += (float)hs[(size_t)s0 * 64 + lane];
    a1 += (float)hs[(size_t)s1 * 64 + lane];
    a2 += (float)hs[(size_t)s2 * 64 + lane];
    a3 += (float)hs[(size_t)s3 * 64 + lane];
  }
  for (; j < end; ++j) a0 += (float)hs[(size_t)csr[j] * 64 + lane];
  float val = dnorm[v] * ((a0 + a1) + (a2 + a3)) + bias[lane];
  hout[(size_t)v * 64 + lane] = fmaxf(val, 0.f);
}

__global__ __launch_bounds__(256) void gather_agg_pool_kernel(
    const half_t* __restrict__ hs, const int* __restrict__ rowptr,
    const int* __restrict__ csr, const float* __restrict__ dnorm,
    const float* __restrict__ bias, const int* __restrict__ batch,
    float* __restrict__ pooled, int N) {
  const int lane = threadIdx.x & 63;
  const int wave = __builtin_amdgcn_readfirstlane((int)(threadIdx.x >> 6));
  int v = blockIdx.x * 4 + wave;
  if (v >= N) return;
  int beg = rowptr[v], end = rowptr[v + 1];
  float a0 = (float)hs[(size_t)v * 64 + lane], a1 = 0.f, a2 = 0.f, a3 = 0.f;
  int j = beg;
  for (; j + 4 <= end; j += 4) {
    int s0 = csr[j], s1 = csr[j + 1], s2 = csr[j + 2], s3 = csr[j + 3];
    a0 += (float)hs[(size_t)s0 * 64 + lane];
    a1 += (float)hs[(size_t)s1 * 64 + lane];
    a2 += (float)hs[(size_t)s2 * 64 + lane];
    a3 += (float)hs[(size_t)s3 * 64 + lane];
  }
  for (; j < end; ++j) a0 += (float)hs[(size_t)csr[j] * 64 + lane];
  float val = dnorm[v] * ((a0 + a1) + (a2 + a3)) + bias[lane];
  val = fmaxf(val, 0.f);
  atomicAdd(&pooled[(size_t)batch[v] * 64 + lane], val);
}

// ---------------- Final FC ----------------
__global__ __launch_bounds__(256) void final_fc_kernel(
    const float* __restrict__ pooled, const int* __restrict__ batch,
    const float* __restrict__ fcW, const float* __restrict__ fcb,
    float* __restrict__ out, int G, int N) {
  int t = blockIdx.x * 256 + threadIdx.x;
  if (t < G * 2) {
    int g = t >> 1, c = t & 1;
    int lo = 0, hi = N;
    while (lo < hi) { int m = (lo + hi) >> 1; if (batch[m] < g) lo = m + 1; else hi = m; }
    int lb = lo;
    lo = 0; hi = N;
    while (lo < hi) { int m = (lo + hi) >> 1; if (batch[m] <= g) lo = m + 1; else hi = m; }
    int cntg = lo - lb;
    float inv = 1.0f / fmaxf((float)cntg, 1.0f);
    float acc = fcb[c];
#pragma unroll
    for (int h = 0; h < 64; ++h)
      acc = fmaf(pooled[g * 64 + h] * inv, fcW[h * 2 + c], acc);
    out[t] = acc;
  }
}

extern "C" void kernel_launch(void* const* d_in, const int* in_sizes, int n_in,
                              void* d_out, int out_size, void* d_ws, size_t ws_size,
                              hipStream_t stream) {
  const float* x   = (const float*)d_in[0];
  const int*   ei  = (const int*)d_in[1];
  const int*   bat = (const int*)d_in[2];
  const float* W1  = (const float*)d_in[3];
  const float* b1  = (const float*)d_in[4];
  const float* W2  = (const float*)d_in[5];
  const float* b2  = (const float*)d_in[6];
  const float* fcW = (const float*)d_in[7];
  const float* fcb = (const float*)d_in[8];
  float* out = (float*)d_out;

  const int N = in_sizes[0] / F_IN;      // 100000
  const int E = in_sizes[1] / 2;         // 3200000
  const int G = out_size / 2;            // 128
  const int* src = ei;
  const int* dst = ei + E;
  const int nb  = (N + BRANGE - 1) >> BR_SHIFT;   // 782 buckets

  auto aln = [](size_t v) { return (v + 63) & ~(size_t)63; };
  char* w = (char*)d_ws;
  int*    entries = (int*)w;     w += aln((size_t)nb * BCAP * 4);
  int*    gcur    = (int*)w;     w += aln((size_t)nb * 4);
  int*    bbase   = (int*)w;     w += aln((size_t)nb * 4);
  int*    rowptr  = (int*)w;     w += aln((size_t)(N + 1) * 4);
  float*  dnorm   = (float*)w;   w += aln((size_t)N * 4);
  int*    csr     = (int*)w;     w += aln((size_t)E * 4);
  half_t* hs      = (half_t*)w;  w += aln((size_t)N * 64 * 2);
  float*  h1      = (float*)w;   w += aln((size_t)N * 64 * 4);
  float*  pooled  = (float*)w;   w += aln((size_t)G * 64 * 4);
  short*  whi1    = (short*)w;   w += aln((size_t)F_IN * 64 * 2);
  short*  wlo1    = (short*)w;   w += aln((size_t)F_IN * 64 * 2);
  short*  whi2    = (short*)w;   w += aln((size_t)HDIM * 64 * 2);
  short*  wlo2    = (short*)w;   w += aln((size_t)HDIM * 64 * 2);

  hipMemsetAsync(gcur, 0, (size_t)nb * 4, stream);
  hipMemsetAsync(pooled, 0, (size_t)G * 64 * 4, stream);

  // W fragment prep
  wfrag_kernel<F_IN><<<(F_IN * 64 * 8 / 8 + 255) / 256, 256, 0, stream>>>(W1, whi1, wlo1);
  wfrag_kernel<HDIM><<<(HDIM * 64 * 8 / 8 + 255) / 256, 256, 0, stream>>>(W2, whi2, wlo2);

  // CSR build
  bin_kernel<<<(E + CHUNK - 1) / CHUNK, 256, 0, stream>>>(
      src, dst, gcur, entries, E, nb);
  bucket_scan_kernel<<<1, 256, 0, stream>>>(gcur, bbase, rowptr, nb, N, E);
  csr_build_kernel<<<nb, 256, 0, stream>>>(entries, gcur, bbase, rowptr,
                                           dnorm, csr, N);

  // layer 1
  mfma_gemm_kernel<F_IN, half_t><<<(N + 63) / 64, 512, 0, stream>>>(
      x, whi1, wlo1, dnorm, hs, N);
  gather_agg_kernel<<<(N + 3) / 4, 256, 0, stream>>>(hs, rowptr, csr, dnorm, b1, h1, N);

  // layer 2 (epilogue fused with pooling)
  mfma_gemm_kernel<HDIM, half_t><<<(N + 63) / 64, 512, 0, stream>>>(
      h1, whi2, wlo2, dnorm, hs, N);
  gather_agg_pool_kernel<<<(N + 3) / 4, 256, 0, stream>>>(hs, rowptr, csr, dnorm, b2, bat, pooled, N);

  // FC
  final_fc_kernel<<<1, 256, 0, stream>>>(pooled, bat, fcW, fcb, out, G, N);
}